// Round 6
// baseline (1121.520 us; speedup 1.0000x reference)
//
#include <hip/hip_runtime.h>

#define DEVINL __device__ __forceinline__

typedef __attribute__((ext_vector_type(8))) short s16x8;
typedef __attribute__((ext_vector_type(4))) float f32x4;

DEVINL unsigned short f2bf(float f) {
  union { float f; unsigned u; } v; v.f = f;
  unsigned r = v.u + 0x7FFFu + ((v.u >> 16) & 1u);
  return (unsigned short)(r >> 16);
}

DEVINL float wave_sum(float v) {
#pragma unroll
  for (int o = 32; o > 0; o >>= 1) v += __shfl_xor(v, o, 64);
  return v;
}

// ------- weight prep: fp32 -> bf16, stack wq|wk; fold softmax scale into Q ----
__global__ __launch_bounds__(256) void prep_kernel(
    const float* __restrict__ wq, const float* __restrict__ wk,
    const float* __restrict__ wv, const float* __restrict__ wo,
    const float* __restrict__ bq, const float* __restrict__ bk,
    unsigned short* __restrict__ wqk, unsigned short* __restrict__ wvb,
    unsigned short* __restrict__ wob, float* __restrict__ bqk) {
  const float scale = 0.04419417382415922f;   // 512^-0.5
  int i = blockIdx.x * 256 + threadIdx.x;
  wqk[i]          = f2bf(wq[i] * scale);
  wqk[262144 + i] = f2bf(wk[i]);
  wvb[i] = f2bf(wv[i]);
  wob[i] = f2bf(wo[i]);
  if (i < 512) { bqk[i] = bq[i] * scale; bqk[512 + i] = bk[i]; }
}

// ---------------- GroupNorm stats: one block per (b,g) ----------------
__global__ __launch_bounds__(256) void gn_stats_kernel(
    const float* __restrict__ x, float* __restrict__ stats) {
  int bg = blockIdx.x;
  const float4* p = (const float4*)(x + (long)bg * 65536);
  float s = 0.f, ss = 0.f;
#pragma unroll 8
  for (int i = 0; i < 64; ++i) {
    float4 v = p[threadIdx.x + 256 * i];
    s  += v.x + v.y + v.z + v.w;
    ss += v.x*v.x + v.y*v.y + v.z*v.z + v.w*v.w;
  }
  __shared__ float red[8];
  float w1 = wave_sum(s), w2 = wave_sum(ss);
  int wave = threadIdx.x >> 6;
  if ((threadIdx.x & 63) == 0) { red[wave] = w1; red[4 + wave] = w2; }
  __syncthreads();
  if (threadIdx.x == 0) {
    float S1 = red[0] + red[1] + red[2] + red[3];
    float S2 = red[4] + red[5] + red[6] + red[7];
    float mu = S1 * (1.f / 65536.f);
    float var = S2 * (1.f / 65536.f) - mu * mu;
    stats[bg * 2]     = mu;
    stats[bg * 2 + 1] = rsqrtf(var + 1e-5f);
  }
}

// ------- GroupNorm normalize + transpose: h_t[b][n][c] bf16 ------
__global__ __launch_bounds__(256) void gn_norm_kernel(
    const float* __restrict__ x, const float* __restrict__ stats,
    const float* __restrict__ gamma, const float* __restrict__ beta,
    unsigned short* __restrict__ hout) {
  int b = blockIdx.y;
  int n0 = blockIdx.x * 128;
  int tid = threadIdx.x;
  __shared__ unsigned short lt[128][33];
  const float* xb = x + (long)b * (512L * 4096);
  unsigned short* hb = hout + (long)b * (4096L * 512);
  for (int cc0 = 0; cc0 < 512; cc0 += 32) {
#pragma unroll
    for (int i = 0; i < 4; ++i) {
      int idx = tid + 256 * i;
      int c = idx >> 5, nf = idx & 31;
      int ch = cc0 + c;
      float4 v = *(const float4*)(xb + (long)ch * 4096 + n0 + nf * 4);
      float mu = stats[(b * 32 + (ch >> 4)) * 2];
      float rs = stats[(b * 32 + (ch >> 4)) * 2 + 1];
      float ga = gamma[ch] * rs;
      float be = beta[ch] - mu * ga;
      int nl = nf * 4;
      lt[nl + 0][c] = f2bf(v.x * ga + be);
      lt[nl + 1][c] = f2bf(v.y * ga + be);
      lt[nl + 2][c] = f2bf(v.z * ga + be);
      lt[nl + 3][c] = f2bf(v.w * ga + be);
    }
    __syncthreads();
#pragma unroll
    for (int i = 0; i < 2; ++i) {
      int idx = tid + 256 * i;
      int row = idx >> 2, part = idx & 3;
      union { uint4 u; unsigned short s[8]; } o;
#pragma unroll
      for (int j = 0; j < 8; ++j) o.s[j] = lt[row][part * 8 + j];
      *(uint4*)(hb + (long)(n0 + row) * 512 + cc0 + part * 8) = o.u;
    }
    __syncthreads();
  }
}

// ---------------- NT GEMM: Out[i][j] = sum_k A[i][k]*B[j][k] -------------
#define BM 128
#define BN 128
#define BKD 64

enum { EPI_BF16 = 0, EPI_BF16_COLBIAS = 1, EPI_BF16_ROWBIAS = 2,
       EPI_F32_SCALE = 3, EPI_F32_RES = 4 };

DEVINL void stage128x64(const unsigned short* g, int ld, unsigned short* l, int tid) {
  int wave = tid >> 6;
#pragma unroll
  for (int it = 0; it < 4; ++it) {
    int seg = it * 256 + tid;
    int row = seg >> 3, ks = seg & 7;
    const unsigned short* gp = g + (long)row * ld + ks * 8;
    unsigned short* lp = l + (it * 256 + wave * 64) * 8;
    __builtin_amdgcn_global_load_lds(
        (const __attribute__((address_space(1))) void*)gp,
        (__attribute__((address_space(3))) void*)lp, 16, 0, 0);
  }
}

template <int EPI>
__global__ __launch_bounds__(256, 2) void gemm_nt(
    const unsigned short* __restrict__ A, long strideA, int lda,
    const unsigned short* __restrict__ B, long strideB, int ldb,
    void* __restrict__ C, long strideC, int ldc, int K,
    const float* __restrict__ bias, float scale,
    const float* __restrict__ resid, long strideR) {
  __shared__ __align__(16) unsigned short lA[BM * BKD];
  __shared__ __align__(16) unsigned short lB[BN * BKD];
  int z = blockIdx.z;
  const unsigned short* Ab = A + (long)z * strideA + (long)blockIdx.y * BM * lda;
  const unsigned short* Bb = B + (long)z * strideB + (long)blockIdx.x * BN * ldb;
  int tid = threadIdx.x;
  int lane = tid & 63, wave = tid >> 6;
  int wm = (wave >> 1) * 64, wn = (wave & 1) * 64;
  int lr = lane & 15;
  int lk = (lane >> 4) * 8;

  f32x4 acc[4][4];
#pragma unroll
  for (int i = 0; i < 4; ++i)
#pragma unroll
    for (int j = 0; j < 4; ++j) acc[i][j] = (f32x4){0.f, 0.f, 0.f, 0.f};

  for (int k0 = 0; k0 < K; k0 += BKD) {
    __syncthreads();
    stage128x64(Ab + k0, lda, lA, tid);
    stage128x64(Bb + k0, ldb, lB, tid);
    __syncthreads();
#pragma unroll
    for (int kk = 0; kk < 2; ++kk) {
      s16x8 af[4], bfr[4];
#pragma unroll
      for (int i = 0; i < 4; ++i)
        af[i] = *(const s16x8*)&lA[(wm + i * 16 + lr) * BKD + kk * 32 + lk];
#pragma unroll
      for (int i = 0; i < 4; ++i)
        bfr[i] = *(const s16x8*)&lB[(wn + i * 16 + lr) * BKD + kk * 32 + lk];
#pragma unroll
      for (int mi = 0; mi < 4; ++mi)
#pragma unroll
        for (int ni = 0; ni < 4; ++ni)
          acc[mi][ni] = __builtin_amdgcn_mfma_f32_16x16x32_bf16(
              af[mi], bfr[ni], acc[mi][ni], 0, 0, 0);
    }
  }

  int rbase = blockIdx.y * BM + wm + (lane >> 4) * 4;
  int cbase = blockIdx.x * BN + wn + lr;
  long cb = (long)z * strideC;
#pragma unroll
  for (int mi = 0; mi < 4; ++mi) {
#pragma unroll
    for (int ni = 0; ni < 4; ++ni) {
      int col = cbase + ni * 16;
#pragma unroll
      for (int r = 0; r < 4; ++r) {
        int row = rbase + mi * 16 + r;
        float val = acc[mi][ni][r];
        long off = cb + (long)row * ldc + col;
        if constexpr (EPI == EPI_BF16) {
          ((unsigned short*)C)[off] = f2bf(val);
        } else if constexpr (EPI == EPI_BF16_COLBIAS) {
          ((unsigned short*)C)[off] = f2bf(val + bias[col]);
        } else if constexpr (EPI == EPI_BF16_ROWBIAS) {
          ((unsigned short*)C)[off] = f2bf(val + bias[row]);
        } else if constexpr (EPI == EPI_F32_SCALE) {
          ((float*)C)[off] = val * scale;
        } else {
          ((float*)C)[off] =
              val + bias[row] + resid[(long)z * strideR + (long)row * ldc + col];
        }
      }
    }
  }
}

// -------- fused flash attention v3: V from L2, 1 barrier/tile, defer-max ----
// grid 256: b = bid&7, qb = bid>>3. 512 threads = 8 waves.
// QK: wave w owns q-rows qb*128 + w*16..+15, KVBLK=32. PV: wave grid 2x4.
DEVINL void stage_k32(const unsigned short* qkb, unsigned short* dst,
                      int kv0, int tid, int wv) {
#pragma unroll
  for (int it = 0; it < 4; ++it) {
    int s = it * 512 + tid;
    int row = s >> 6, c16 = s & 63;
    const unsigned short* gp = qkb + (long)(kv0 + row) * 1024 + 512 + ((c16 ^ (row & 7)) * 8);
    unsigned short* lp = dst + (it * 512 + wv * 64) * 8;
    __builtin_amdgcn_global_load_lds(
        (const __attribute__((address_space(1))) void*)gp,
        (__attribute__((address_space(3))) void*)lp, 16, 0, 0);
  }
}

__global__ __launch_bounds__(512, 2) void flash3_kernel(
    const unsigned short* __restrict__ qk, const unsigned short* __restrict__ v,
    unsigned short* __restrict__ o) {
  __shared__ __align__(16) unsigned short lK[2][32 * 512];   // 2 x 32 KB
  __shared__ __align__(16) unsigned short lP[2][128 * 64];   // 2 x 16 KB
  __shared__ float lCorr[2][128];
  __shared__ float lInv[128];

  int bid = blockIdx.x;
  int b = bid & 7, qb = bid >> 3;
  const unsigned short* qkb = qk + (long)b * 4096 * 1024;
  const unsigned short* vb  = v  + (long)b * 512 * 4096;
  int tid = threadIdx.x, lane = tid & 63, wv = tid >> 6;
  int g = lane >> 4, qi = lane & 15;
  int q0 = qb * 128;
  int wq = wv >> 2, wc = wv & 3;     // PV wave grid 2x4

  // persistent Q B-frags (pre-scaled): qf[kk] = Q[q0+wv*16+qi][kk*32+g*8..+7]
  s16x8 qf[16];
  {
    const unsigned short* qrow = qkb + (long)(q0 + wv * 16 + qi) * 1024 + g * 8;
#pragma unroll
    for (int kk = 0; kk < 16; ++kk) qf[kk] = *(const s16x8*)(qrow + kk * 32);
  }

  f32x4 accO[4][8];
#pragma unroll
  for (int i = 0; i < 4; ++i)
#pragma unroll
    for (int j = 0; j < 8; ++j) accO[i][j] = (f32x4){0.f, 0.f, 0.f, 0.f};
  float m_run = -3.0e38f, l_run = 0.f;

  stage_k32(qkb, &lK[0][0], 0, tid, wv);
  __syncthreads();

  int cur = 0;
  for (int t = 0; t < 128; ++t) {
    int nxt = t < 127 ? t + 1 : 127;
    stage_k32(qkb, &lK[cur ^ 1][0], nxt * 32, tid, wv);

    // ---- QK^T (swapped): lane owns q-col (wv*16+qi), 8 kv values ----
    f32x4 sacc[2];
    sacc[0] = (f32x4){0.f, 0.f, 0.f, 0.f};
    sacc[1] = (f32x4){0.f, 0.f, 0.f, 0.f};
    const char* lkc = (const char*)&lK[cur][0];
    __builtin_amdgcn_s_setprio(1);
#pragma unroll
    for (int kk = 0; kk < 16; ++kk) {
      int ko = (kk * 64 + g * 16) ^ ((qi & 7) << 4);
#pragma unroll
      for (int sub = 0; sub < 2; ++sub) {
        const s16x8 kf = *(const s16x8*)(lkc + (sub * 16 + qi) * 1024 + ko);
        sacc[sub] = __builtin_amdgcn_mfma_f32_16x16x32_bf16(kf, qf[kk], sacc[sub], 0, 0, 0);
      }
    }
    __builtin_amdgcn_s_setprio(0);

    // ---- issue V loads for this tile (L2-resident; regs used after barrier)
    s16x8 vf[8];
#pragma unroll
    for (int ct = 0; ct < 8; ++ct) {
      int c = (wc * 8 + ct) * 16 + qi;
      vf[ct] = *(const s16x8*)(vb + (long)c * 4096 + t * 32 + g * 8);
    }

    // ---- online softmax with defer-max (THR=8) ----
    float mx = -3.0e38f;
#pragma unroll
    for (int sub = 0; sub < 2; ++sub)
#pragma unroll
      for (int r = 0; r < 4; ++r) mx = fmaxf(mx, sacc[sub][r]);
    mx = fmaxf(mx, __shfl_xor(mx, 16, 64));
    mx = fmaxf(mx, __shfl_xor(mx, 32, 64));
    float corr;
    if (mx <= m_run + 8.f) {
      corr = 1.f;
    } else {
      corr = __expf(m_run - mx);
      m_run = mx;
    }
    float rowsum = 0.f;
#pragma unroll
    for (int sub = 0; sub < 2; ++sub)
#pragma unroll
      for (int r = 0; r < 4; ++r) {
        float p = __expf(sacc[sub][r] - m_run);
        sacc[sub][r] = p;
        rowsum += p;
      }
    rowsum += __shfl_xor(rowsum, 16, 64);
    rowsum += __shfl_xor(rowsum, 32, 64);
    l_run = l_run * corr + rowsum;
    if (g == 0) lCorr[t & 1][wv * 16 + qi] = corr;

    // ---- P write (bf16, swizzled) to buffer t&1 ----
    {
      int q = wv * 16 + qi;
      char* pw = (char*)&lP[t & 1][0] + q * 128;
#pragma unroll
      for (int sub = 0; sub < 2; ++sub) {
        uint2 pk;
        pk.x = (unsigned)f2bf(sacc[sub][0]) | ((unsigned)f2bf(sacc[sub][1]) << 16);
        pk.y = (unsigned)f2bf(sacc[sub][2]) | ((unsigned)f2bf(sacc[sub][3]) << 16);
        int chunk = (sub * 2 + (g >> 1)) ^ (q & 7);
        *(uint2*)(pw + (chunk << 4) + (g & 1) * 8) = pk;
      }
    }
    __syncthreads();   // P/corr visible; K(t+1) + vf drained

    // ---- PV: accO[i][ct] += P[q-tile i][32kv] * V[ct][32kv] ----
    const char* lpc = (const char*)&lP[t & 1][0];
    __builtin_amdgcn_s_setprio(1);
#pragma unroll
    for (int i = 0; i < 4; ++i) {
      f32x4 cr = *(const f32x4*)&lCorr[t & 1][wq * 64 + i * 16 + g * 4];
      if (__any(cr[0] != 1.f || cr[1] != 1.f || cr[2] != 1.f || cr[3] != 1.f)) {
#pragma unroll
        for (int j = 0; j < 8; ++j)
#pragma unroll
          for (int r = 0; r < 4; ++r) accO[i][j][r] *= cr[r];
      }
      int q = (wq * 4 + i) * 16 + qi;
      const s16x8 pf = *(const s16x8*)(lpc + q * 128 + ((g ^ (q & 7)) << 4));
#pragma unroll
      for (int ct = 0; ct < 8; ++ct)
        accO[i][ct] = __builtin_amdgcn_mfma_f32_16x16x32_bf16(
            pf, vf[ct], accO[i][ct], 0, 0, 0);
    }
    __builtin_amdgcn_s_setprio(0);
    cur ^= 1;
  }

  // epilogue: distribute 1/l via LDS, scale, store o[b][q][c]
  if (g == 0) lInv[wv * 16 + qi] = 1.0f / l_run;
  __syncthreads();
  unsigned short* ob = o + (long)b * (4096L * 512) + (long)q0 * 512;
#pragma unroll
  for (int i = 0; i < 4; ++i) {
    f32x4 fr = *(const f32x4*)&lInv[wq * 64 + i * 16 + g * 4];
#pragma unroll
    for (int j = 0; j < 8; ++j)
#pragma unroll
      for (int r = 0; r < 4; ++r)
        ob[(long)(wq * 64 + i * 16 + g * 4 + r) * 512 + wc * 128 + j * 16 + qi] =
            f2bf(accO[i][j][r] * fr[r]);
  }
}

// ---------------- launcher ----------------
extern "C" void kernel_launch(void* const* d_in, const int* in_sizes, int n_in,
                              void* d_out, int out_size, void* d_ws, size_t ws_size,
                              hipStream_t stream) {
  const float* x   = (const float*)d_in[0];
  const float* gsc = (const float*)d_in[1];
  const float* gbi = (const float*)d_in[2];
  const float* wq  = (const float*)d_in[3];
  const float* bq  = (const float*)d_in[4];
  const float* wk  = (const float*)d_in[5];
  const float* bk  = (const float*)d_in[6];
  const float* wv  = (const float*)d_in[7];
  const float* bv  = (const float*)d_in[8];
  const float* wo  = (const float*)d_in[9];
  const float* bo  = (const float*)d_in[10];
  float* out = (float*)d_out;

  char* w = (char*)d_ws;
  unsigned short* wqk  = (unsigned short*)(w);
  unsigned short* wvb  = (unsigned short*)(w + 1048576);
  unsigned short* wob  = (unsigned short*)(w + 1572864);
  float*          bqk  = (float*)(w + 2097152);
  float*          stats= (float*)(w + 2101248);
  char* big = w + 4194304;
  unsigned short* h_t  = (unsigned short*)(big);               // 33,554,432
  unsigned short* qkb  = (unsigned short*)(big + 33554432);    // 67,108,864
  unsigned short* vbuf = (unsigned short*)(big + 100663296);   // 33,554,432
  unsigned short* o_t  = (unsigned short*)(big + 134217728);   // 33,554,432

  prep_kernel<<<1024, 256, 0, stream>>>(wq, wk, wv, wo, bq, bk, wqk, wvb, wob, bqk);
  gn_stats_kernel<<<256, 256, 0, stream>>>(x, stats);
  gn_norm_kernel<<<dim3(32, 8), 256, 0, stream>>>(x, stats, gsc, gbi, h_t);

  const long HB = 4096L * 512;
  const long XB = 512L * 4096;

  gemm_nt<EPI_BF16_COLBIAS><<<dim3(8, 32, 8), 256, 0, stream>>>(
      h_t, HB, 512, wqk, 0, 512, qkb, 4096L * 1024, 1024, 512, bqk, 1.f, nullptr, 0);
  gemm_nt<EPI_BF16_ROWBIAS><<<dim3(32, 4, 8), 256, 0, stream>>>(
      wvb, 0, 512, h_t, HB, 512, vbuf, XB, 4096, 512, bv, 1.f, nullptr, 0);

  flash3_kernel<<<256, 512, 0, stream>>>(qkb, vbuf, o_t);

  gemm_nt<EPI_F32_RES><<<dim3(32, 4, 8), 256, 0, stream>>>(
      wob, 0, 512, o_t, HB, 512, out, XB, 4096, 512, bo, 1.f, x, XB);
}